// Round 1
// baseline (2754.076 us; speedup 1.0000x reference)
//
#include <hip/hip_runtime.h>

// weighted_graph_conv: out[n,t,o] = sum_{e: dst[e]==n} ew[t,e] * nf[src[e],t,:] dot W[o,:]  + bias[o]
// Round 1: scatter (atomicAdd) into h == d_out, then in-place per-row 64x64 linear.

#define F_DIM 64
#define TF 256  // T*F = 4*64

// One wave (64 lanes) per edge; each lane handles one float4 of the edge's
// 256-float message. src/dst are wave-uniform; reads/atomics coalesced (1KB/wave).
__global__ __launch_bounds__(256) void scatter_kernel(
    const float4* __restrict__ nf4,   // (N, T, F) as float4: N*64 per row-of-256
    const float*  __restrict__ ew,    // (T, E)
    const int*    __restrict__ src,
    const int*    __restrict__ dst,
    float*        __restrict__ h,     // (N, T, F) accumulator (pre-zeroed)
    int E) {
  int idx = blockIdx.x * 256 + threadIdx.x;
  int e = idx >> 6;
  if (e >= E) return;
  int r = idx & 63;        // lane within edge
  int t = r >> 4;          // 0..3
  int q = r & 15;          // float4 index within the 64-float feature row

  int s = src[e];
  int d = dst[e];
  float w = ew[t * E + e];
  float4 v = nf4[(size_t)s * 64 + t * 16 + q];

  float* hp = h + (size_t)d * TF + t * F_DIM + q * 4;
  atomicAdd(hp + 0, w * v.x);
  atomicAdd(hp + 1, w * v.y);
  atomicAdd(hp + 2, w * v.z);
  atomicAdd(hp + 3, w * v.w);
}

// In-place per-row linear: row (64 floats) -> W @ row + bias.
// W staged transposed in LDS with +1 padding (conflict-free reads).
// 32 rows per block, 4 rows in flight (256 threads = 4 x 64).
__global__ __launch_bounds__(256) void linear_kernel(
    float* __restrict__ h,            // (nrows, 64), transformed in place
    const float* __restrict__ W,      // (64, 64) row-major: W[o][f]
    const float* __restrict__ bias,   // (64,)
    int nrows) {
  __shared__ float Wt[64 * 65];       // Wt[f*65 + o] = W[o*64 + f]
  __shared__ float rows[4][64];

  int tid = threadIdx.x;
  for (int i = tid; i < 4096; i += 256) {
    int o = i >> 6, f = i & 63;
    Wt[f * 65 + o] = W[i];
  }
  int rr = tid >> 6;   // 0..3  (row slot)
  int o  = tid & 63;   // output feature
  float b = bias[o];
  int rbase = blockIdx.x * 32;

  for (int r0 = 0; r0 < 32; r0 += 4) {
    int row = rbase + r0 + rr;
    __syncthreads();                          // prev iter done reading `rows` (and Wt ready)
    if (row < nrows) rows[rr][o] = h[(size_t)row * F_DIM + o];
    __syncthreads();
    if (row < nrows) {
      float acc = b;
      #pragma unroll
      for (int f = 0; f < 64; ++f)
        acc += rows[rr][f] * Wt[f * 65 + o];  // rows: broadcast; Wt: 2-way (free)
      h[(size_t)row * F_DIM + o] = acc;
    }
  }
}

extern "C" void kernel_launch(void* const* d_in, const int* in_sizes, int n_in,
                              void* d_out, int out_size, void* d_ws, size_t ws_size,
                              hipStream_t stream) {
  const float* nf   = (const float*)d_in[0];  // (N, T, 64) f32
  const float* ew   = (const float*)d_in[1];  // (T, E) f32
  const int*   src  = (const int*)d_in[2];    // (E,)
  const int*   dst  = (const int*)d_in[3];    // (E,)
  const float* W    = (const float*)d_in[4];  // (64, 64)
  const float* bias = (const float*)d_in[5];  // (64,)
  float* out = (float*)d_out;                 // (N, T, 64) f32

  int E = in_sizes[2];
  int nrows = out_size / F_DIM;               // N*T

  // h accumulator lives in d_out; must zero every call (harness poisons once).
  hipMemsetAsync(d_out, 0, (size_t)out_size * sizeof(float), stream);

  int nblk = (E * 64 + 255) / 256;            // one wave per edge
  scatter_kernel<<<nblk, 256, 0, stream>>>((const float4*)nf, ew, src, dst, out, E);

  int lblk = (nrows + 31) / 32;
  linear_kernel<<<lblk, 256, 0, stream>>>(out, W, bias, nrows);
}

// Round 2
// 438.083 us; speedup vs baseline: 6.2866x; 6.2866x over previous
//
#include <hip/hip_runtime.h>

// weighted_graph_conv, round 2: CSR-by-dst gather instead of atomic scatter.
// out[n,t,o] = bias[o] + sum_{e: dst[e]==n} ew[t,e] * (nf[src[e],t,:] . W[o,:])
//
// Phases (all on `stream`):
//  1. histogram dst -> cnt        (int atomics, cheap)
//  2. exclusive scan cnt -> off   (single block)
//  3. bucket fill edge ids        (int atomics on cursors)
//  4. gather: one wave per dst node, accumulate 256-float row in registers,
//     write h (== d_out) once. No float atomics.
//  5. in-place 64x64 linear + bias.

#define F_DIM 64
#define TF 256  // T*F

__global__ __launch_bounds__(256) void hist_kernel(
    const int* __restrict__ dst, int* __restrict__ cnt, int E) {
  int e = blockIdx.x * 256 + threadIdx.x;
  if (e < E) atomicAdd(&cnt[dst[e]], 1);
}

// Single-block exclusive scan over N elements (N ~ 50K): chunked Hillis-Steele.
__global__ __launch_bounds__(1024) void scan_kernel(
    const int* __restrict__ cnt, int* __restrict__ off, int N) {
  __shared__ int buf[1024];
  __shared__ int carry;
  int tid = threadIdx.x;
  if (tid == 0) carry = 0;
  __syncthreads();
  for (int base = 0; base < N; base += 1024) {
    int i = base + tid;
    int v = (i < N) ? cnt[i] : 0;
    buf[tid] = v;
    __syncthreads();
    #pragma unroll
    for (int s = 1; s < 1024; s <<= 1) {
      int t = (tid >= s) ? buf[tid - s] : 0;
      __syncthreads();
      buf[tid] += t;
      __syncthreads();
    }
    int incl = buf[tid];
    if (i < N) off[i] = carry + incl - v;   // exclusive
    __syncthreads();                        // everyone has read carry
    if (tid == 1023) carry += buf[1023];    // chunk total
    __syncthreads();                        // new carry visible
  }
  if (tid == 0) off[N] = carry;
}

__global__ __launch_bounds__(256) void fill_kernel(
    const int* __restrict__ dst, const int* __restrict__ off,
    int* __restrict__ cursor, int* __restrict__ eids, int E) {
  int e = blockIdx.x * 256 + threadIdx.x;
  if (e < E) {
    int d = dst[e];
    int pos = off[d] + atomicAdd(&cursor[d], 1);
    eids[pos] = e;
  }
}

// One wave per destination node. Lane r: t = r>>4, q = r&15 -> one float4 of
// the node's (T=4, F=64) = 256-float row. Accumulate in registers, store once.
__global__ __launch_bounds__(256) void gather_kernel(
    const float4* __restrict__ nf4,    // (N, 64) float4 per node
    const float*  __restrict__ ew,     // (T, E)
    const int*    __restrict__ src,
    const int*    __restrict__ off,    // (N+1,)
    const int*    __restrict__ eids,   // (E,)
    float4*       __restrict__ h4,     // (N, 64) float4 output rows
    int N, int E) {
  int idx = blockIdx.x * 256 + threadIdx.x;
  int n = idx >> 6;
  if (n >= N) return;
  int r = idx & 63;
  int t = r >> 4;          // 0..3
  int q = r & 15;          // float4 slot within feature row

  int beg = off[n], end = off[n + 1];
  float4 acc = make_float4(0.f, 0.f, 0.f, 0.f);
  for (int p = beg; p < end; ++p) {
    int e = eids[p];                       // wave-uniform
    int s = src[e];                        // wave-uniform
    float w = ew[t * E + e];               // broadcast within 16-lane group
    float4 v = nf4[(size_t)s * 64 + t * 16 + q];  // 1KB coalesced per wave
    acc.x += w * v.x; acc.y += w * v.y;
    acc.z += w * v.z; acc.w += w * v.w;
  }
  h4[(size_t)n * 64 + t * 16 + q] = acc;
}

// In-place per-row linear: row (64 floats) -> W @ row + bias.
__global__ __launch_bounds__(256) void linear_kernel(
    float* __restrict__ h, const float* __restrict__ W,
    const float* __restrict__ bias, int nrows) {
  __shared__ float Wt[64 * 65];   // Wt[f*65 + o] = W[o*64 + f]
  __shared__ float rows[4][64];
  int tid = threadIdx.x;
  for (int i = tid; i < 4096; i += 256) {
    int o = i >> 6, f = i & 63;
    Wt[f * 65 + o] = W[i];
  }
  int rr = tid >> 6;
  int o  = tid & 63;
  float b = bias[o];
  int rbase = blockIdx.x * 32;
  for (int r0 = 0; r0 < 32; r0 += 4) {
    int row = rbase + r0 + rr;
    __syncthreads();
    if (row < nrows) rows[rr][o] = h[(size_t)row * F_DIM + o];
    __syncthreads();
    if (row < nrows) {
      float acc = b;
      #pragma unroll
      for (int f = 0; f < 64; ++f)
        acc += rows[rr][f] * Wt[f * 65 + o];
      h[(size_t)row * F_DIM + o] = acc;
    }
  }
}

extern "C" void kernel_launch(void* const* d_in, const int* in_sizes, int n_in,
                              void* d_out, int out_size, void* d_ws, size_t ws_size,
                              hipStream_t stream) {
  const float* nf   = (const float*)d_in[0];  // (N, T, 64) f32
  const float* ew   = (const float*)d_in[1];  // (T, E) f32
  const int*   src  = (const int*)d_in[2];
  const int*   dst  = (const int*)d_in[3];
  const float* W    = (const float*)d_in[4];
  const float* bias = (const float*)d_in[5];
  float* out = (float*)d_out;

  int E = in_sizes[2];
  int N = out_size / TF;           // out is (N, T, 64)
  int nrows = out_size / F_DIM;    // N*T

  // Workspace layout (ints): [cnt N][cursor N][off N+1][eids E]
  int* cnt    = (int*)d_ws;
  int* cursor = cnt + N;
  int* off    = cursor + N;
  int* eids   = off + (N + 1);

  // zero cnt + cursor each call (harness poisons ws once, never re-zeros)
  hipMemsetAsync(cnt, 0, (size_t)(2 * N) * sizeof(int), stream);

  int eblk = (E + 255) / 256;
  hist_kernel<<<eblk, 256, 0, stream>>>(dst, cnt, E);
  scan_kernel<<<1, 1024, 0, stream>>>(cnt, off, N);
  fill_kernel<<<eblk, 256, 0, stream>>>(dst, off, cursor, eids, E);

  int gblk = (N * 64 + 255) / 256;   // one wave per node
  gather_kernel<<<gblk, 256, 0, stream>>>((const float4*)nf, ew, src, off, eids,
                                          (float4*)out, N, E);

  int lblk = (nrows + 31) / 32;
  linear_kernel<<<lblk, 256, 0, stream>>>(out, W, bias, nrows);
}

// Round 3
// 255.675 us; speedup vs baseline: 10.7718x; 1.7134x over previous
//
#include <hip/hip_runtime.h>

// weighted_graph_conv, round 3:
//  - parallel 3-kernel scan (was single-block, ~150us serial)
//  - CSR fill packs (src, w[4]) per edge-slot -> gather reads sequential streams
//  - linear fused into pre-pass: nfb = bf16(W @ nf_row); gather writes out+bias directly
//  - gather 4-wide unrolled: 4 independent nf fetches in flight per wave
// Fallback (small ws): f32 gather of raw nf into out, then separate linear pass.

#define F_DIM 64
#define TF 256  // T*F

__device__ __forceinline__ unsigned short f2bf(float x) {
  unsigned u = __float_as_uint(x);
  return (unsigned short)((u + 0x7FFF + ((u >> 16) & 1)) >> 16);  // RNE
}
__device__ __forceinline__ float bf2f(unsigned short b) {
  return __uint_as_float(((unsigned)b) << 16);
}

__global__ __launch_bounds__(256) void hist_kernel(
    const int* __restrict__ dst, int* __restrict__ cnt, int E) {
  int e = blockIdx.x * 256 + threadIdx.x;
  if (e < E) atomicAdd(&cnt[dst[e]], 1);
}

// Block-level exclusive scan (1024/block) + per-block totals.
__global__ __launch_bounds__(1024) void scanA_kernel(
    const int* __restrict__ cnt, int* __restrict__ off, int* __restrict__ bsum, int N) {
  __shared__ int wsum[16];
  int tid = threadIdx.x;
  int i = blockIdx.x * 1024 + tid;
  int v = (i < N) ? cnt[i] : 0;
  int lane = tid & 63;
  int incl = v;
  #pragma unroll
  for (int s = 1; s < 64; s <<= 1) {
    int t = __shfl_up(incl, s, 64);
    if (lane >= s) incl += t;
  }
  int w = tid >> 6;
  if (lane == 63) wsum[w] = incl;
  __syncthreads();
  if (w == 0) {
    int x = (lane < 16) ? wsum[lane] : 0;
    #pragma unroll
    for (int s = 1; s < 16; s <<= 1) {
      int t = __shfl_up(x, s, 64);
      if (lane >= s) x += t;
    }
    if (lane < 16) wsum[lane] = x;  // inclusive wave prefix
  }
  __syncthreads();
  int wpre = (w == 0) ? 0 : wsum[w - 1];
  if (i < N) off[i] = wpre + incl - v;          // block-local exclusive
  if (tid == 1023) bsum[blockIdx.x] = wpre + incl;  // block total
}

// Exclusive scan of <=64 block totals, in place (one wave).
__global__ __launch_bounds__(64) void scanB_kernel(int* __restrict__ bsum, int nb) {
  int lane = threadIdx.x;
  int v = (lane < nb) ? bsum[lane] : 0;
  int incl = v;
  #pragma unroll
  for (int s = 1; s < 64; s <<= 1) {
    int t = __shfl_up(incl, s, 64);
    if (lane >= s) incl += t;
  }
  if (lane < nb) bsum[lane] = incl - v;
}

__global__ __launch_bounds__(1024) void scanC_kernel(
    int* __restrict__ off, const int* __restrict__ bsum, int N, int E) {
  int i = blockIdx.x * 1024 + threadIdx.x;
  if (i < N) off[i] += bsum[blockIdx.x];
  if (i == N) off[N] = E;  // grand total
}

// Bucket-fill CSR slots with packed per-edge data. Reuses cnt as a countdown
// cursor (atomicSub), so no separate cursor array / extra memset.
__global__ __launch_bounds__(256) void fill_kernel(
    const int* __restrict__ dst, const int* __restrict__ src,
    const float* __restrict__ ew, const int* __restrict__ off,
    int* __restrict__ cnt, int* __restrict__ psrc, float4* __restrict__ pw, int E) {
  int e = blockIdx.x * 256 + threadIdx.x;
  if (e < E) {
    int d = dst[e];
    int pos = off[d] + atomicSub(&cnt[d], 1) - 1;
    psrc[pos] = src[e];
    pw[pos] = make_float4(ew[e], ew[E + e], ew[2 * E + e], ew[3 * E + e]);
  }
}

// Pre-transform: nfb[row,:] = bf16(W @ nf[row,:]). Bias added later in gather.
__global__ __launch_bounds__(256) void transform_kernel(
    const float* __restrict__ nf, const float* __restrict__ W,
    unsigned short* __restrict__ nfb, int nrows) {
  __shared__ float Wt[64 * 65];   // Wt[f*65+o] = W[o*64+f]
  __shared__ float rows[4][64];
  int tid = threadIdx.x;
  for (int i = tid; i < 4096; i += 256) Wt[(i & 63) * 65 + (i >> 6)] = W[i];
  int rr = tid >> 6, o = tid & 63;
  int rbase = blockIdx.x * 32;
  for (int r0 = 0; r0 < 32; r0 += 4) {
    int row = rbase + r0 + rr;
    __syncthreads();
    if (row < nrows) rows[rr][o] = nf[(size_t)row * F_DIM + o];
    __syncthreads();
    if (row < nrows) {
      float acc = 0.f;
      #pragma unroll
      for (int f = 0; f < 64; ++f) acc += rows[rr][f] * Wt[f * 65 + o];
      nfb[(size_t)row * F_DIM + o] = f2bf(acc);
    }
  }
}

// One wave per node; lane r: t=r>>4, q=r&15 owns 4 output features (q*4..+3)
// of timestep t. Sequential psrc/pw streams; 4 independent nf fetches in flight.
__global__ __launch_bounds__(256) void gather_bf16_kernel(
    const ushort4* __restrict__ nfb,   // (N*T*64)/4 transformed bf16 rows
    const int* __restrict__ psrc, const float* __restrict__ pwf,  // pw as scalar floats
    const int* __restrict__ off, const float4* __restrict__ bias4,
    float4* __restrict__ out4, int N) {
  int idx = blockIdx.x * 256 + threadIdx.x;
  int n = idx >> 6;
  if (n >= N) return;
  int r = idx & 63, t = r >> 4, q = r & 15;
  int beg = off[n], end = off[n + 1];
  float4 acc = make_float4(0.f, 0.f, 0.f, 0.f);
  int p = beg;
  for (; p + 4 <= end; p += 4) {
    int s0 = psrc[p], s1 = psrc[p + 1], s2 = psrc[p + 2], s3 = psrc[p + 3];
    float w0 = pwf[4 * p + t], w1 = pwf[4 * (p + 1) + t];
    float w2 = pwf[4 * (p + 2) + t], w3 = pwf[4 * (p + 3) + t];
    ushort4 v0 = nfb[(size_t)s0 * 64 + t * 16 + q];
    ushort4 v1 = nfb[(size_t)s1 * 64 + t * 16 + q];
    ushort4 v2 = nfb[(size_t)s2 * 64 + t * 16 + q];
    ushort4 v3 = nfb[(size_t)s3 * 64 + t * 16 + q];
    acc.x += w0 * bf2f(v0.x) + w1 * bf2f(v1.x) + w2 * bf2f(v2.x) + w3 * bf2f(v3.x);
    acc.y += w0 * bf2f(v0.y) + w1 * bf2f(v1.y) + w2 * bf2f(v2.y) + w3 * bf2f(v3.y);
    acc.z += w0 * bf2f(v0.z) + w1 * bf2f(v1.z) + w2 * bf2f(v2.z) + w3 * bf2f(v3.z);
    acc.w += w0 * bf2f(v0.w) + w1 * bf2f(v1.w) + w2 * bf2f(v2.w) + w3 * bf2f(v3.w);
  }
  for (; p < end; ++p) {
    int s = psrc[p];
    float w = pwf[4 * p + t];
    ushort4 v = nfb[(size_t)s * 64 + t * 16 + q];
    acc.x += w * bf2f(v.x); acc.y += w * bf2f(v.y);
    acc.z += w * bf2f(v.z); acc.w += w * bf2f(v.w);
  }
  float4 b = bias4[q];
  acc.x += b.x; acc.y += b.y; acc.z += b.z; acc.w += b.w;
  out4[(size_t)n * 64 + t * 16 + q] = acc;
}

// ---- f32 fallback path (small ws): gather raw nf into out, then linear ----
__global__ __launch_bounds__(256) void gather_f32_kernel(
    const float4* __restrict__ nf4, const int* __restrict__ psrc,
    const float* __restrict__ pwf, const int* __restrict__ off,
    float4* __restrict__ h4, int N) {
  int idx = blockIdx.x * 256 + threadIdx.x;
  int n = idx >> 6;
  if (n >= N) return;
  int r = idx & 63, t = r >> 4, q = r & 15;
  int beg = off[n], end = off[n + 1];
  float4 acc = make_float4(0.f, 0.f, 0.f, 0.f);
  int p = beg;
  for (; p + 2 <= end; p += 2) {
    int s0 = psrc[p], s1 = psrc[p + 1];
    float w0 = pwf[4 * p + t], w1 = pwf[4 * (p + 1) + t];
    float4 v0 = nf4[(size_t)s0 * 64 + t * 16 + q];
    float4 v1 = nf4[(size_t)s1 * 64 + t * 16 + q];
    acc.x += w0 * v0.x + w1 * v1.x; acc.y += w0 * v0.y + w1 * v1.y;
    acc.z += w0 * v0.z + w1 * v1.z; acc.w += w0 * v0.w + w1 * v1.w;
  }
  for (; p < end; ++p) {
    int s = psrc[p];
    float w = pwf[4 * p + t];
    float4 v = nf4[(size_t)s * 64 + t * 16 + q];
    acc.x += w * v.x; acc.y += w * v.y; acc.z += w * v.z; acc.w += w * v.w;
  }
  h4[(size_t)n * 64 + t * 16 + q] = acc;
}

__global__ __launch_bounds__(256) void linear_kernel(
    float* __restrict__ h, const float* __restrict__ W,
    const float* __restrict__ bias, int nrows) {
  __shared__ float Wt[64 * 65];
  __shared__ float rows[4][64];
  int tid = threadIdx.x;
  for (int i = tid; i < 4096; i += 256) Wt[(i & 63) * 65 + (i >> 6)] = W[i];
  int rr = tid >> 6, o = tid & 63;
  float b = bias[o];
  int rbase = blockIdx.x * 32;
  for (int r0 = 0; r0 < 32; r0 += 4) {
    int row = rbase + r0 + rr;
    __syncthreads();
    if (row < nrows) rows[rr][o] = h[(size_t)row * F_DIM + o];
    __syncthreads();
    if (row < nrows) {
      float acc = b;
      #pragma unroll
      for (int f = 0; f < 64; ++f) acc += rows[rr][f] * Wt[f * 65 + o];
      h[(size_t)row * F_DIM + o] = acc;
    }
  }
}

extern "C" void kernel_launch(void* const* d_in, const int* in_sizes, int n_in,
                              void* d_out, int out_size, void* d_ws, size_t ws_size,
                              hipStream_t stream) {
  const float* nf   = (const float*)d_in[0];  // (N, T, 64)
  const float* ew   = (const float*)d_in[1];  // (T, E)
  const int*   src  = (const int*)d_in[2];
  const int*   dst  = (const int*)d_in[3];
  const float* W    = (const float*)d_in[4];  // (64, 64)
  const float* bias = (const float*)d_in[5];  // (64,)
  float* out = (float*)d_out;

  int E = in_sizes[2];
  int N = out_size / TF;
  int nrows = out_size / F_DIM;  // N*T
  int nfelems = nrows * F_DIM;   // N*T*64

  // ws layout: [cnt N][off N+1][bsum 64] ints | pw float4[E] (16B aligned) | psrc int[E] | nfb ushort[N*T*64]
  char* wsb = (char*)d_ws;
  int* cnt  = (int*)wsb;
  int* off  = cnt + N;
  int* bsum = off + (N + 1);
  size_t ofs = ((size_t)(2 * N + 1 + 64) * 4 + 15) & ~(size_t)15;
  float4* pw = (float4*)(wsb + ofs);          ofs += (size_t)E * 16;
  int* psrc  = (int*)(wsb + ofs);             ofs += (size_t)E * 4;
  ofs = (ofs + 15) & ~(size_t)15;
  unsigned short* nfb = (unsigned short*)(wsb + ofs);
  size_t need_bf16 = ofs + (size_t)nfelems * 2;
  bool use_bf16 = ws_size >= need_bf16;

  hipMemsetAsync(cnt, 0, (size_t)N * sizeof(int), stream);

  int eblk = (E + 255) / 256;
  hist_kernel<<<eblk, 256, 0, stream>>>(dst, cnt, E);

  int sblk = (N + 1023) / 1024;
  scanA_kernel<<<sblk, 1024, 0, stream>>>(cnt, off, bsum, N);
  scanB_kernel<<<1, 64, 0, stream>>>(bsum, sblk);
  scanC_kernel<<<(N + 1024) / 1024, 1024, 0, stream>>>(off, bsum, N, E);

  fill_kernel<<<eblk, 256, 0, stream>>>(dst, src, ew, off, cnt, psrc, pw, E);

  int gblk = (N * 64 + 255) / 256;
  if (use_bf16) {
    transform_kernel<<<(nrows + 31) / 32, 256, 0, stream>>>(nf, W, nfb, nrows);
    gather_bf16_kernel<<<gblk, 256, 0, stream>>>(
        (const ushort4*)nfb, psrc, (const float*)pw, off,
        (const float4*)bias, (float4*)out, N);
  } else {
    gather_f32_kernel<<<gblk, 256, 0, stream>>>(
        (const float4*)nf, psrc, (const float*)pw, off, (float4*)out, N);
    linear_kernel<<<(nrows + 31) / 32, 256, 0, stream>>>(out, W, bias, nrows);
  }
}

// Round 5
// 247.578 us; speedup vs baseline: 11.1241x; 1.0327x over previous
//
#include <hip/hip_runtime.h>

// weighted_graph_conv, round 5 (= round 4 with nontemporal builtin fix):
//  - transform: 256 rows/block in LDS, 4x16 register tile per thread
//  - nfb 512B-aligned -> each gathered bf16 row is exactly 4 cachelines
//  - nontemporal loads for psrc/pw streams, NT store for out (via ext_vector f4n)

#define F_DIM 64
#define TF 256  // T*F

typedef float f4n __attribute__((ext_vector_type(4)));  // native vec for NT builtins

__device__ __forceinline__ unsigned short f2bf(float x) {
  unsigned u = __float_as_uint(x);
  return (unsigned short)((u + 0x7FFF + ((u >> 16) & 1)) >> 16);  // RNE
}
__device__ __forceinline__ float bf2f(unsigned short b) {
  return __uint_as_float(((unsigned)b) << 16);
}
__device__ __forceinline__ void fma4(float4& a, float s, float4 w) {
  a.x += s * w.x; a.y += s * w.y; a.z += s * w.z; a.w += s * w.w;
}

__global__ __launch_bounds__(256) void hist_kernel(
    const int* __restrict__ dst, int* __restrict__ cnt, int E) {
  int e = blockIdx.x * 256 + threadIdx.x;
  if (e < E) atomicAdd(&cnt[dst[e]], 1);
}

__global__ __launch_bounds__(1024) void scanA_kernel(
    const int* __restrict__ cnt, int* __restrict__ off, int* __restrict__ bsum, int N) {
  __shared__ int wsum[16];
  int tid = threadIdx.x;
  int i = blockIdx.x * 1024 + tid;
  int v = (i < N) ? cnt[i] : 0;
  int lane = tid & 63;
  int incl = v;
  #pragma unroll
  for (int s = 1; s < 64; s <<= 1) {
    int t = __shfl_up(incl, s, 64);
    if (lane >= s) incl += t;
  }
  int w = tid >> 6;
  if (lane == 63) wsum[w] = incl;
  __syncthreads();
  if (w == 0) {
    int x = (lane < 16) ? wsum[lane] : 0;
    #pragma unroll
    for (int s = 1; s < 16; s <<= 1) {
      int t = __shfl_up(x, s, 64);
      if (lane >= s) x += t;
    }
    if (lane < 16) wsum[lane] = x;
  }
  __syncthreads();
  int wpre = (w == 0) ? 0 : wsum[w - 1];
  if (i < N) off[i] = wpre + incl - v;
  if (tid == 1023) bsum[blockIdx.x] = wpre + incl;
}

__global__ __launch_bounds__(64) void scanB_kernel(int* __restrict__ bsum, int nb) {
  int lane = threadIdx.x;
  int v = (lane < nb) ? bsum[lane] : 0;
  int incl = v;
  #pragma unroll
  for (int s = 1; s < 64; s <<= 1) {
    int t = __shfl_up(incl, s, 64);
    if (lane >= s) incl += t;
  }
  if (lane < nb) bsum[lane] = incl - v;
}

__global__ __launch_bounds__(1024) void scanC_kernel(
    int* __restrict__ off, const int* __restrict__ bsum, int N, int E) {
  int i = blockIdx.x * 1024 + threadIdx.x;
  if (i < N) off[i] += bsum[blockIdx.x];
  if (i == N) off[N] = E;
}

__global__ __launch_bounds__(256) void fill_kernel(
    const int* __restrict__ dst, const int* __restrict__ src,
    const float* __restrict__ ew, const int* __restrict__ off,
    int* __restrict__ cnt, int* __restrict__ psrc, f4n* __restrict__ pw, int E) {
  int e = blockIdx.x * 256 + threadIdx.x;
  if (e < E) {
    int d = dst[e];
    int pos = off[d] + atomicSub(&cnt[d], 1) - 1;
    __builtin_nontemporal_store(src[e], &psrc[pos]);
    f4n w4 = {ew[e], ew[E + e], ew[2 * E + e], ew[3 * E + e]};
    __builtin_nontemporal_store(w4, &pw[pos]);
  }
}

// Transform: nfb[row,:] = bf16(W @ nf[row,:]).
// 256 rows/block in LDS; thread tile = 4 rows x 16 outputs (16 float4 accs).
__global__ __launch_bounds__(256) void transform_kernel(
    const float4* __restrict__ nf4, const float* __restrict__ W,
    unsigned short* __restrict__ nfb, int nrows) {
  __shared__ float Wt[64 * 64];     // Wt[f*64+o] = W[o*64+f]
  __shared__ float rows[256][65];   // +1 pad
  int tid = threadIdx.x;
  #pragma unroll
  for (int i = tid; i < 4096; i += 256) Wt[(i & 63) * 64 + (i >> 6)] = W[i];
  int rbase = blockIdx.x * 256;
  int nr = min(256, nrows - rbase);
  for (int i = tid; i < nr * 16; i += 256) {
    int r = i >> 4, q = i & 15;
    float4 v = nf4[(size_t)(rbase + r) * 16 + q];
    rows[r][q * 4 + 0] = v.x; rows[r][q * 4 + 1] = v.y;
    rows[r][q * 4 + 2] = v.z; rows[r][q * 4 + 3] = v.w;
  }
  __syncthreads();

  int oq = tid & 3;        // output chunk: o in [oq*16, oq*16+16)
  int r0 = (tid >> 2) * 4; // 4 rows per thread
  float4 acc[4][4];
  #pragma unroll
  for (int j = 0; j < 4; ++j)
    #pragma unroll
    for (int c = 0; c < 4; ++c) acc[j][c] = make_float4(0.f, 0.f, 0.f, 0.f);

  const float4* Wt4 = (const float4*)Wt;  // Wt4[f*16 + o4]
  #pragma unroll 8
  for (int f = 0; f < 64; ++f) {
    float4 w0 = Wt4[f * 16 + oq * 4 + 0];
    float4 w1 = Wt4[f * 16 + oq * 4 + 1];
    float4 w2 = Wt4[f * 16 + oq * 4 + 2];
    float4 w3 = Wt4[f * 16 + oq * 4 + 3];
    #pragma unroll
    for (int j = 0; j < 4; ++j) {
      float rv = rows[r0 + j][f];   // garbage if r0+j >= nr; result unused
      fma4(acc[j][0], rv, w0);
      fma4(acc[j][1], rv, w1);
      fma4(acc[j][2], rv, w2);
      fma4(acc[j][3], rv, w3);
    }
  }

  int obase = oq * 16;
  #pragma unroll
  for (int j = 0; j < 4; ++j) {
    if (r0 + j < nr) {
      size_t rowoff = (size_t)(rbase + r0 + j) * 64 + obase;
      #pragma unroll
      for (int c = 0; c < 4; ++c) {
        float4 a = acc[j][c];
        ushort4 u = make_ushort4(f2bf(a.x), f2bf(a.y), f2bf(a.z), f2bf(a.w));
        *reinterpret_cast<ushort4*>(&nfb[rowoff + c * 4]) = u;
      }
    }
  }
}

// One wave per node; lane r: t=r>>4, q=r&15. 4-wide unrolled gather.
__global__ __launch_bounds__(256) void gather_bf16_kernel(
    const ushort4* __restrict__ nfb,
    const int* __restrict__ psrc, const float* __restrict__ pwf,
    const int* __restrict__ off, const float4* __restrict__ bias4,
    f4n* __restrict__ out4, int N) {
  int idx = blockIdx.x * 256 + threadIdx.x;
  int n = idx >> 6;
  if (n >= N) return;
  int r = idx & 63, t = r >> 4, q = r & 15;
  int beg = off[n], end = off[n + 1];
  float4 acc = make_float4(0.f, 0.f, 0.f, 0.f);
  int p = beg;
  for (; p + 4 <= end; p += 4) {
    int s0 = __builtin_nontemporal_load(&psrc[p]);
    int s1 = __builtin_nontemporal_load(&psrc[p + 1]);
    int s2 = __builtin_nontemporal_load(&psrc[p + 2]);
    int s3 = __builtin_nontemporal_load(&psrc[p + 3]);
    float w0 = __builtin_nontemporal_load(&pwf[4 * p + t]);
    float w1 = __builtin_nontemporal_load(&pwf[4 * (p + 1) + t]);
    float w2 = __builtin_nontemporal_load(&pwf[4 * (p + 2) + t]);
    float w3 = __builtin_nontemporal_load(&pwf[4 * (p + 3) + t]);
    ushort4 v0 = nfb[(size_t)s0 * 64 + t * 16 + q];
    ushort4 v1 = nfb[(size_t)s1 * 64 + t * 16 + q];
    ushort4 v2 = nfb[(size_t)s2 * 64 + t * 16 + q];
    ushort4 v3 = nfb[(size_t)s3 * 64 + t * 16 + q];
    acc.x += w0 * bf2f(v0.x) + w1 * bf2f(v1.x) + w2 * bf2f(v2.x) + w3 * bf2f(v3.x);
    acc.y += w0 * bf2f(v0.y) + w1 * bf2f(v1.y) + w2 * bf2f(v2.y) + w3 * bf2f(v3.y);
    acc.z += w0 * bf2f(v0.z) + w1 * bf2f(v1.z) + w2 * bf2f(v2.z) + w3 * bf2f(v3.z);
    acc.w += w0 * bf2f(v0.w) + w1 * bf2f(v1.w) + w2 * bf2f(v2.w) + w3 * bf2f(v3.w);
  }
  for (; p < end; ++p) {
    int s = __builtin_nontemporal_load(&psrc[p]);
    float w = __builtin_nontemporal_load(&pwf[4 * p + t]);
    ushort4 v = nfb[(size_t)s * 64 + t * 16 + q];
    acc.x += w * bf2f(v.x); acc.y += w * bf2f(v.y);
    acc.z += w * bf2f(v.z); acc.w += w * bf2f(v.w);
  }
  float4 b = bias4[q];
  f4n res = {acc.x + b.x, acc.y + b.y, acc.z + b.z, acc.w + b.w};
  __builtin_nontemporal_store(res, &out4[(size_t)n * 64 + t * 16 + q]);
}

// ---- f32 fallback path (small ws) ----
__global__ __launch_bounds__(256) void gather_f32_kernel(
    const float4* __restrict__ nf4, const int* __restrict__ psrc,
    const float* __restrict__ pwf, const int* __restrict__ off,
    float4* __restrict__ h4, int N) {
  int idx = blockIdx.x * 256 + threadIdx.x;
  int n = idx >> 6;
  if (n >= N) return;
  int r = idx & 63, t = r >> 4, q = r & 15;
  int beg = off[n], end = off[n + 1];
  float4 acc = make_float4(0.f, 0.f, 0.f, 0.f);
  int p = beg;
  for (; p + 2 <= end; p += 2) {
    int s0 = psrc[p], s1 = psrc[p + 1];
    float w0 = pwf[4 * p + t], w1 = pwf[4 * (p + 1) + t];
    float4 v0 = nf4[(size_t)s0 * 64 + t * 16 + q];
    float4 v1 = nf4[(size_t)s1 * 64 + t * 16 + q];
    acc.x += w0 * v0.x + w1 * v1.x; acc.y += w0 * v0.y + w1 * v1.y;
    acc.z += w0 * v0.z + w1 * v1.z; acc.w += w0 * v0.w + w1 * v1.w;
  }
  for (; p < end; ++p) {
    int s = psrc[p];
    float w = pwf[4 * p + t];
    float4 v = nf4[(size_t)s * 64 + t * 16 + q];
    acc.x += w * v.x; acc.y += w * v.y; acc.z += w * v.z; acc.w += w * v.w;
  }
  h4[(size_t)n * 64 + t * 16 + q] = acc;
}

__global__ __launch_bounds__(256) void linear_kernel(
    float* __restrict__ h, const float* __restrict__ W,
    const float* __restrict__ bias, int nrows) {
  __shared__ float Wt[64 * 65];
  __shared__ float rows[4][64];
  int tid = threadIdx.x;
  for (int i = tid; i < 4096; i += 256) Wt[(i & 63) * 65 + (i >> 6)] = W[i];
  int rr = tid >> 6, o = tid & 63;
  float b = bias[o];
  int rbase = blockIdx.x * 32;
  for (int r0 = 0; r0 < 32; r0 += 4) {
    int row = rbase + r0 + rr;
    __syncthreads();
    if (row < nrows) rows[rr][o] = h[(size_t)row * F_DIM + o];
    __syncthreads();
    if (row < nrows) {
      float acc = b;
      #pragma unroll
      for (int f = 0; f < 64; ++f) acc += rows[rr][f] * Wt[f * 65 + o];
      h[(size_t)row * F_DIM + o] = acc;
    }
  }
}

extern "C" void kernel_launch(void* const* d_in, const int* in_sizes, int n_in,
                              void* d_out, int out_size, void* d_ws, size_t ws_size,
                              hipStream_t stream) {
  const float* nf   = (const float*)d_in[0];
  const float* ew   = (const float*)d_in[1];
  const int*   src  = (const int*)d_in[2];
  const int*   dst  = (const int*)d_in[3];
  const float* W    = (const float*)d_in[4];
  const float* bias = (const float*)d_in[5];
  float* out = (float*)d_out;

  int E = in_sizes[2];
  int N = out_size / TF;
  int nrows = out_size / F_DIM;   // N*T
  int nfelems = nrows * F_DIM;

  // ws layout: [cnt N][off N+1][bsum 64] | pw f4n[E] | psrc int[E] | nfb (512B-aligned)
  char* wsb = (char*)d_ws;
  int* cnt  = (int*)wsb;
  int* off  = cnt + N;
  int* bsum = off + (N + 1);
  size_t ofs = ((size_t)(2 * N + 1 + 64) * 4 + 15) & ~(size_t)15;
  f4n* pw   = (f4n*)(wsb + ofs);              ofs += (size_t)E * 16;
  int* psrc = (int*)(wsb + ofs);              ofs += (size_t)E * 4;
  ofs = (ofs + 511) & ~(size_t)511;           // row-align nfb: 4 exact cachelines/row
  unsigned short* nfb = (unsigned short*)(wsb + ofs);
  size_t need_bf16 = ofs + (size_t)nfelems * 2;
  bool use_bf16 = ws_size >= need_bf16;

  (void)hipMemsetAsync(cnt, 0, (size_t)N * sizeof(int), stream);

  int eblk = (E + 255) / 256;
  hist_kernel<<<eblk, 256, 0, stream>>>(dst, cnt, E);

  int sblk = (N + 1023) / 1024;
  scanA_kernel<<<sblk, 1024, 0, stream>>>(cnt, off, bsum, N);
  scanB_kernel<<<1, 64, 0, stream>>>(bsum, sblk);
  scanC_kernel<<<(N + 1024) / 1024, 1024, 0, stream>>>(off, bsum, N, E);

  fill_kernel<<<eblk, 256, 0, stream>>>(dst, src, ew, off, cnt, psrc, pw, E);

  int gblk = (N * 64 + 255) / 256;
  if (use_bf16) {
    transform_kernel<<<(nrows + 255) / 256, 256, 0, stream>>>(
        (const float4*)nf, W, nfb, nrows);
    gather_bf16_kernel<<<gblk, 256, 0, stream>>>(
        (const ushort4*)nfb, psrc, (const float*)pw, off,
        (const float4*)bias, (f4n*)out, N);
  } else {
    gather_f32_kernel<<<gblk, 256, 0, stream>>>(
        (const float4*)nf, psrc, (const float*)pw, off, (float4*)out, N);
    linear_kernel<<<(nrows + 31) / 32, 256, 0, stream>>>(out, W, bias, nrows);
  }
}

// Round 7
// 216.630 us; speedup vs baseline: 12.7133x; 1.1429x over previous
//
#include <hip/hip_runtime.h>

// weighted_graph_conv, round 7 (= round 6 minus ALL nontemporal hints):
//  - CSR slot = single 16B packed record {src, w[4] as bf16}
//  - all loads/stores cached — NT store on `out` caused post-timing staleness
//    (validation read saw ~poison for resident lines; absmax ~= max|ref|)

#define F_DIM 64
#define TF 256  // T*F

__device__ __forceinline__ unsigned short f2bf(float x) {
  unsigned u = __float_as_uint(x);
  return (unsigned short)((u + 0x7FFF + ((u >> 16) & 1)) >> 16);  // RNE
}
__device__ __forceinline__ float bf2f(unsigned short b) {
  return __uint_as_float(((unsigned)b) << 16);
}
__device__ __forceinline__ void fma4(float4& a, float s, float4 w) {
  a.x += s * w.x; a.y += s * w.y; a.z += s * w.z; a.w += s * w.w;
}

__global__ __launch_bounds__(256) void hist_kernel(
    const int* __restrict__ dst, int* __restrict__ cnt, int E) {
  int e = blockIdx.x * 256 + threadIdx.x;
  if (e < E) atomicAdd(&cnt[dst[e]], 1);
}

__global__ __launch_bounds__(1024) void scanA_kernel(
    const int* __restrict__ cnt, int* __restrict__ off, int* __restrict__ bsum, int N) {
  __shared__ int wsum[16];
  int tid = threadIdx.x;
  int i = blockIdx.x * 1024 + tid;
  int v = (i < N) ? cnt[i] : 0;
  int lane = tid & 63;
  int incl = v;
  #pragma unroll
  for (int s = 1; s < 64; s <<= 1) {
    int t = __shfl_up(incl, s, 64);
    if (lane >= s) incl += t;
  }
  int w = tid >> 6;
  if (lane == 63) wsum[w] = incl;
  __syncthreads();
  if (w == 0) {
    int x = (lane < 16) ? wsum[lane] : 0;
    #pragma unroll
    for (int s = 1; s < 16; s <<= 1) {
      int t = __shfl_up(x, s, 64);
      if (lane >= s) x += t;
    }
    if (lane < 16) wsum[lane] = x;
  }
  __syncthreads();
  int wpre = (w == 0) ? 0 : wsum[w - 1];
  if (i < N) off[i] = wpre + incl - v;
  if (tid == 1023) bsum[blockIdx.x] = wpre + incl;
}

__global__ __launch_bounds__(64) void scanB_kernel(int* __restrict__ bsum, int nb) {
  int lane = threadIdx.x;
  int v = (lane < nb) ? bsum[lane] : 0;
  int incl = v;
  #pragma unroll
  for (int s = 1; s < 64; s <<= 1) {
    int t = __shfl_up(incl, s, 64);
    if (lane >= s) incl += t;
  }
  if (lane < nb) bsum[lane] = incl - v;
}

__global__ __launch_bounds__(1024) void scanC_kernel(
    int* __restrict__ off, const int* __restrict__ bsum, int N, int E) {
  int i = blockIdx.x * 1024 + threadIdx.x;
  if (i < N) off[i] += bsum[blockIdx.x];
  if (i == N) off[N] = E;
}

// CSR record: x=src, y=(w1|w0) bf16 pair, z=(w3|w2) bf16 pair, w=0.
__global__ __launch_bounds__(256) void fill_kernel(
    const int* __restrict__ dst, const int* __restrict__ src,
    const float* __restrict__ ew, const int* __restrict__ off,
    int* __restrict__ cnt, uint4* __restrict__ rec, int E) {
  int e = blockIdx.x * 256 + threadIdx.x;
  if (e < E) {
    int d = dst[e];
    int pos = off[d] + atomicSub(&cnt[d], 1) - 1;
    unsigned w0 = f2bf(ew[e]),         w1 = f2bf(ew[E + e]);
    unsigned w2 = f2bf(ew[2 * E + e]), w3 = f2bf(ew[3 * E + e]);
    uint4 r;
    r.x = (unsigned)src[e];
    r.y = (w1 << 16) | w0;
    r.z = (w3 << 16) | w2;
    r.w = 0;
    rec[pos] = r;   // single scattered 16B store, cached (L2/L3)
  }
}

// Transform: nfb[row,:] = bf16(W @ nf[row,:]).
// 256 rows/block in LDS; thread tile = 4 rows x 16 outputs.
__global__ __launch_bounds__(256) void transform_kernel(
    const float4* __restrict__ nf4, const float* __restrict__ W,
    unsigned short* __restrict__ nfb, int nrows) {
  __shared__ float Wt[64 * 64];     // Wt[f*64+o] = W[o*64+f]
  __shared__ float rows[256][65];   // +1 pad
  int tid = threadIdx.x;
  #pragma unroll
  for (int i = tid; i < 4096; i += 256) Wt[(i & 63) * 64 + (i >> 6)] = W[i];
  int rbase = blockIdx.x * 256;
  int nr = min(256, nrows - rbase);
  for (int i = tid; i < nr * 16; i += 256) {
    int r = i >> 4, q = i & 15;
    float4 v = nf4[(size_t)(rbase + r) * 16 + q];
    rows[r][q * 4 + 0] = v.x; rows[r][q * 4 + 1] = v.y;
    rows[r][q * 4 + 2] = v.z; rows[r][q * 4 + 3] = v.w;
  }
  __syncthreads();

  int oq = tid & 3;
  int r0 = (tid >> 2) * 4;
  float4 acc[4][4];
  #pragma unroll
  for (int j = 0; j < 4; ++j)
    #pragma unroll
    for (int c = 0; c < 4; ++c) acc[j][c] = make_float4(0.f, 0.f, 0.f, 0.f);

  const float4* Wt4 = (const float4*)Wt;
  #pragma unroll 8
  for (int f = 0; f < 64; ++f) {
    float4 w0 = Wt4[f * 16 + oq * 4 + 0];
    float4 w1 = Wt4[f * 16 + oq * 4 + 1];
    float4 w2 = Wt4[f * 16 + oq * 4 + 2];
    float4 w3 = Wt4[f * 16 + oq * 4 + 3];
    #pragma unroll
    for (int j = 0; j < 4; ++j) {
      float rv = rows[r0 + j][f];
      fma4(acc[j][0], rv, w0);
      fma4(acc[j][1], rv, w1);
      fma4(acc[j][2], rv, w2);
      fma4(acc[j][3], rv, w3);
    }
  }

  int obase = oq * 16;
  #pragma unroll
  for (int j = 0; j < 4; ++j) {
    if (r0 + j < nr) {
      size_t rowoff = (size_t)(rbase + r0 + j) * 64 + obase;
      #pragma unroll
      for (int c = 0; c < 4; ++c) {
        float4 a = acc[j][c];
        ushort4 u = make_ushort4(f2bf(a.x), f2bf(a.y), f2bf(a.z), f2bf(a.w));
        *reinterpret_cast<ushort4*>(&nfb[rowoff + c * 4]) = u;
      }
    }
  }
}

// One wave per node; lane r: t=r>>4, q=r&15. 4-wide unrolled gather.
// Per edge: one broadcast 16B record load + one gathered 8B (half of 128B row).
__global__ __launch_bounds__(256) void gather_bf16_kernel(
    const ushort4* __restrict__ nfb, const uint4* __restrict__ rec,
    const int* __restrict__ off, const float4* __restrict__ bias4,
    float4* __restrict__ out4, int N) {
  int idx = blockIdx.x * 256 + threadIdx.x;
  int n = idx >> 6;
  if (n >= N) return;
  int r = idx & 63, t = r >> 4, q = r & 15;
  int wsel = t >> 1;            // 0: use rec.y, 1: use rec.z
  int wshift = (t & 1) << 4;    // 0 or 16
  int beg = off[n], end = off[n + 1];
  float4 acc = make_float4(0.f, 0.f, 0.f, 0.f);
  int p = beg;
  for (; p + 4 <= end; p += 4) {
    uint4 r0 = rec[p], r1 = rec[p + 1], r2 = rec[p + 2], r3 = rec[p + 3];
    float w0 = __uint_as_float(((wsel ? r0.z : r0.y) >> wshift) << 16);
    float w1 = __uint_as_float(((wsel ? r1.z : r1.y) >> wshift) << 16);
    float w2 = __uint_as_float(((wsel ? r2.z : r2.y) >> wshift) << 16);
    float w3 = __uint_as_float(((wsel ? r3.z : r3.y) >> wshift) << 16);
    ushort4 v0 = nfb[(size_t)r0.x * 64 + t * 16 + q];
    ushort4 v1 = nfb[(size_t)r1.x * 64 + t * 16 + q];
    ushort4 v2 = nfb[(size_t)r2.x * 64 + t * 16 + q];
    ushort4 v3 = nfb[(size_t)r3.x * 64 + t * 16 + q];
    acc.x += w0 * bf2f(v0.x) + w1 * bf2f(v1.x) + w2 * bf2f(v2.x) + w3 * bf2f(v3.x);
    acc.y += w0 * bf2f(v0.y) + w1 * bf2f(v1.y) + w2 * bf2f(v2.y) + w3 * bf2f(v3.y);
    acc.z += w0 * bf2f(v0.z) + w1 * bf2f(v1.z) + w2 * bf2f(v2.z) + w3 * bf2f(v3.z);
    acc.w += w0 * bf2f(v0.w) + w1 * bf2f(v1.w) + w2 * bf2f(v2.w) + w3 * bf2f(v3.w);
  }
  for (; p < end; ++p) {
    uint4 rr = rec[p];
    float w = __uint_as_float(((wsel ? rr.z : rr.y) >> wshift) << 16);
    ushort4 v = nfb[(size_t)rr.x * 64 + t * 16 + q];
    acc.x += w * bf2f(v.x); acc.y += w * bf2f(v.y);
    acc.z += w * bf2f(v.z); acc.w += w * bf2f(v.w);
  }
  float4 b = bias4[q];
  float4 res = make_float4(acc.x + b.x, acc.y + b.y, acc.z + b.z, acc.w + b.w);
  out4[(size_t)n * 64 + t * 16 + q] = res;   // regular cached store
}

// ---- f32 fallback path (small ws): records still bf16-weighted ----
__global__ __launch_bounds__(256) void gather_f32_kernel(
    const float4* __restrict__ nf4, const uint4* __restrict__ rec,
    const int* __restrict__ off, float4* __restrict__ h4, int N) {
  int idx = blockIdx.x * 256 + threadIdx.x;
  int n = idx >> 6;
  if (n >= N) return;
  int r = idx & 63, t = r >> 4, q = r & 15;
  int wsel = t >> 1;
  int wshift = (t & 1) << 4;
  int beg = off[n], end = off[n + 1];
  float4 acc = make_float4(0.f, 0.f, 0.f, 0.f);
  for (int p = beg; p < end; ++p) {
    uint4 rr = rec[p];
    float w = __uint_as_float(((wsel ? rr.z : rr.y) >> wshift) << 16);
    float4 v = nf4[(size_t)rr.x * 64 + t * 16 + q];
    acc.x += w * v.x; acc.y += w * v.y; acc.z += w * v.z; acc.w += w * v.w;
  }
  h4[(size_t)n * 64 + t * 16 + q] = acc;
}

__global__ __launch_bounds__(256) void linear_kernel(
    float* __restrict__ h, const float* __restrict__ W,
    const float* __restrict__ bias, int nrows) {
  __shared__ float Wt[64 * 65];
  __shared__ float rows[4][64];
  int tid = threadIdx.x;
  for (int i = tid; i < 4096; i += 256) Wt[(i & 63) * 65 + (i >> 6)] = W[i];
  int rr = tid >> 6, o = tid & 63;
  float b = bias[o];
  int rbase = blockIdx.x * 32;
  for (int r0 = 0; r0 < 32; r0 += 4) {
    int row = rbase + r0 + rr;
    __syncthreads();
    if (row < nrows) rows[rr][o] = h[(size_t)row * F_DIM + o];
    __syncthreads();
    if (row < nrows) {
      float acc = b;
      #pragma unroll
      for (int f = 0; f < 64; ++f) acc += rows[rr][f] * Wt[f * 65 + o];
      h[(size_t)row * F_DIM + o] = acc;
    }
  }
}

extern "C" void kernel_launch(void* const* d_in, const int* in_sizes, int n_in,
                              void* d_out, int out_size, void* d_ws, size_t ws_size,
                              hipStream_t stream) {
  const float* nf   = (const float*)d_in[0];
  const float* ew   = (const float*)d_in[1];
  const int*   src  = (const int*)d_in[2];
  const int*   dst  = (const int*)d_in[3];
  const float* W    = (const float*)d_in[4];
  const float* bias = (const float*)d_in[5];
  float* out = (float*)d_out;

  int E = in_sizes[2];
  int N = out_size / TF;
  int nrows = out_size / F_DIM;   // N*T
  int nfelems = nrows * F_DIM;

  // ws layout: [cnt N][off N+1][bsum 64] | rec uint4[E] | nfb (512B-aligned)
  char* wsb = (char*)d_ws;
  int* cnt  = (int*)wsb;
  int* off  = cnt + N;
  int* bsum = off + (N + 1);
  size_t ofs = ((size_t)(2 * N + 1 + 64) * 4 + 15) & ~(size_t)15;
  uint4* rec = (uint4*)(wsb + ofs);           ofs += (size_t)E * 16;
  ofs = (ofs + 511) & ~(size_t)511;           // row-align nfb: exact cachelines/row
  unsigned short* nfb = (unsigned short*)(wsb + ofs);
  size_t need_bf16 = ofs + (size_t)nfelems * 2;
  bool use_bf16 = ws_size >= need_bf16;

  (void)hipMemsetAsync(cnt, 0, (size_t)N * sizeof(int), stream);

  int eblk = (E + 255) / 256;
  hist_kernel<<<eblk, 256, 0, stream>>>(dst, cnt, E);

  int sblk = (N + 1023) / 1024;
  scanA_kernel<<<sblk, 1024, 0, stream>>>(cnt, off, bsum, N);
  scanB_kernel<<<1, 64, 0, stream>>>(bsum, sblk);
  scanC_kernel<<<(N + 1024) / 1024, 1024, 0, stream>>>(off, bsum, N, E);

  fill_kernel<<<eblk, 256, 0, stream>>>(dst, src, ew, off, cnt, rec, E);

  int gblk = (N * 64 + 255) / 256;
  if (use_bf16) {
    transform_kernel<<<(nrows + 255) / 256, 256, 0, stream>>>(
        (const float4*)nf, W, nfb, nrows);
    gather_bf16_kernel<<<gblk, 256, 0, stream>>>(
        (const ushort4*)nfb, rec, off, (const float4*)bias, (float4*)out, N);
  } else {
    gather_f32_kernel<<<gblk, 256, 0, stream>>>(
        (const float4*)nf, rec, off, (float4*)out, N);
    linear_kernel<<<(nrows + 31) / 32, 256, 0, stream>>>(out, W, bias, nrows);
  }
}

// Round 8
// 210.219 us; speedup vs baseline: 13.1010x; 1.0305x over previous
//
#include <hip/hip_runtime.h>

// weighted_graph_conv, round 8: transform rewritten as LDS-free wave-per-row GEMV.
//  - lane o holds W[o][0..63] in 64 VGPRs (per-wave, amortized over ~24 rows)
//  - row features are wave-uniform -> readfirstlane'd pointer -> s_load to SGPRs
//  - per f: one v_fmac acc, s_rv, v_w  (optimal VALU density; 4 acc chains for ILP)
//  - prior version: 83KB LDS -> 1 block/CU -> 8% occupancy, LDS-pipe-bound, 66us

#define F_DIM 64
#define TF 256  // T*F

__device__ __forceinline__ unsigned short f2bf(float x) {
  unsigned u = __float_as_uint(x);
  return (unsigned short)((u + 0x7FFF + ((u >> 16) & 1)) >> 16);  // RNE
}
__device__ __forceinline__ float bf2f(unsigned short b) {
  return __uint_as_float(((unsigned)b) << 16);
}

__global__ __launch_bounds__(256) void hist_kernel(
    const int* __restrict__ dst, int* __restrict__ cnt, int E) {
  int e = blockIdx.x * 256 + threadIdx.x;
  if (e < E) atomicAdd(&cnt[dst[e]], 1);
}

__global__ __launch_bounds__(1024) void scanA_kernel(
    const int* __restrict__ cnt, int* __restrict__ off, int* __restrict__ bsum, int N) {
  __shared__ int wsum[16];
  int tid = threadIdx.x;
  int i = blockIdx.x * 1024 + tid;
  int v = (i < N) ? cnt[i] : 0;
  int lane = tid & 63;
  int incl = v;
  #pragma unroll
  for (int s = 1; s < 64; s <<= 1) {
    int t = __shfl_up(incl, s, 64);
    if (lane >= s) incl += t;
  }
  int w = tid >> 6;
  if (lane == 63) wsum[w] = incl;
  __syncthreads();
  if (w == 0) {
    int x = (lane < 16) ? wsum[lane] : 0;
    #pragma unroll
    for (int s = 1; s < 16; s <<= 1) {
      int t = __shfl_up(x, s, 64);
      if (lane >= s) x += t;
    }
    if (lane < 16) wsum[lane] = x;
  }
  __syncthreads();
  int wpre = (w == 0) ? 0 : wsum[w - 1];
  if (i < N) off[i] = wpre + incl - v;
  if (tid == 1023) bsum[blockIdx.x] = wpre + incl;
}

__global__ __launch_bounds__(64) void scanB_kernel(int* __restrict__ bsum, int nb) {
  int lane = threadIdx.x;
  int v = (lane < nb) ? bsum[lane] : 0;
  int incl = v;
  #pragma unroll
  for (int s = 1; s < 64; s <<= 1) {
    int t = __shfl_up(incl, s, 64);
    if (lane >= s) incl += t;
  }
  if (lane < nb) bsum[lane] = incl - v;
}

__global__ __launch_bounds__(1024) void scanC_kernel(
    int* __restrict__ off, const int* __restrict__ bsum, int N, int E) {
  int i = blockIdx.x * 1024 + threadIdx.x;
  if (i < N) off[i] += bsum[blockIdx.x];
  if (i == N) off[N] = E;
}

// CSR record: x=src, y=(w1|w0) bf16 pair, z=(w3|w2) bf16 pair, w=0.
__global__ __launch_bounds__(256) void fill_kernel(
    const int* __restrict__ dst, const int* __restrict__ src,
    const float* __restrict__ ew, const int* __restrict__ off,
    int* __restrict__ cnt, uint4* __restrict__ rec, int E) {
  int e = blockIdx.x * 256 + threadIdx.x;
  if (e < E) {
    int d = dst[e];
    int pos = off[d] + atomicSub(&cnt[d], 1) - 1;
    unsigned w0 = f2bf(ew[e]),         w1 = f2bf(ew[E + e]);
    unsigned w2 = f2bf(ew[2 * E + e]), w3 = f2bf(ew[3 * E + e]);
    uint4 r;
    r.x = (unsigned)src[e];
    r.y = (w1 << 16) | w0;
    r.z = (w3 << 16) | w2;
    r.w = 0;
    rec[pos] = r;   // single scattered 16B store, cached (L2/L3)
  }
}

// Transform: nfb[row,:] = bf16(W @ nf[row,:]).
// One wave per row-iteration; lane o owns output column o.
// W column in VGPRs; row features via wave-uniform scalar loads (SGPR broadcast).
__global__ __launch_bounds__(256) void transform_kernel(
    const float* __restrict__ nf, const float* __restrict__ W,
    unsigned short* __restrict__ nfb, int nrows) {
  int lane = threadIdx.x & 63;
  int gwave = blockIdx.x * 4 + (threadIdx.x >> 6);
  int nwaves = gridDim.x * 4;

  // wcol[f] = W[lane][f]  (contiguous 256B per lane; 16KB total, L2-hot)
  float wcol[64];
  #pragma unroll
  for (int c = 0; c < 16; ++c) {
    float4 v = *reinterpret_cast<const float4*>(&W[lane * 64 + c * 4]);
    wcol[c * 4 + 0] = v.x; wcol[c * 4 + 1] = v.y;
    wcol[c * 4 + 2] = v.z; wcol[c * 4 + 3] = v.w;
  }

  for (int row = gwave; row < nrows; row += nwaves) {
    int urow = __builtin_amdgcn_readfirstlane(row);   // provably uniform -> s_load
    const float* rp = nf + (size_t)urow * F_DIM;
    float a0 = 0.f, a1 = 0.f, a2 = 0.f, a3 = 0.f;     // 4 chains: break FMA latency
    #pragma unroll
    for (int f = 0; f < 64; f += 4) {
      a0 = fmaf(rp[f + 0], wcol[f + 0], a0);
      a1 = fmaf(rp[f + 1], wcol[f + 1], a1);
      a2 = fmaf(rp[f + 2], wcol[f + 2], a2);
      a3 = fmaf(rp[f + 3], wcol[f + 3], a3);
    }
    nfb[(size_t)urow * F_DIM + lane] = f2bf((a0 + a1) + (a2 + a3));
  }
}

// One wave per node; lane r: t=r>>4, q=r&15. 4-wide unrolled gather.
// Per edge: one broadcast 16B record load + one gathered 8B (half of 128B row).
__global__ __launch_bounds__(256) void gather_bf16_kernel(
    const ushort4* __restrict__ nfb, const uint4* __restrict__ rec,
    const int* __restrict__ off, const float4* __restrict__ bias4,
    float4* __restrict__ out4, int N) {
  int idx = blockIdx.x * 256 + threadIdx.x;
  int n = idx >> 6;
  if (n >= N) return;
  int r = idx & 63, t = r >> 4, q = r & 15;
  int wsel = t >> 1;            // 0: use rec.y, 1: use rec.z
  int wshift = (t & 1) << 4;    // 0 or 16
  int beg = off[n], end = off[n + 1];
  float4 acc = make_float4(0.f, 0.f, 0.f, 0.f);
  int p = beg;
  for (; p + 4 <= end; p += 4) {
    uint4 r0 = rec[p], r1 = rec[p + 1], r2 = rec[p + 2], r3 = rec[p + 3];
    float w0 = __uint_as_float(((wsel ? r0.z : r0.y) >> wshift) << 16);
    float w1 = __uint_as_float(((wsel ? r1.z : r1.y) >> wshift) << 16);
    float w2 = __uint_as_float(((wsel ? r2.z : r2.y) >> wshift) << 16);
    float w3 = __uint_as_float(((wsel ? r3.z : r3.y) >> wshift) << 16);
    ushort4 v0 = nfb[(size_t)r0.x * 64 + t * 16 + q];
    ushort4 v1 = nfb[(size_t)r1.x * 64 + t * 16 + q];
    ushort4 v2 = nfb[(size_t)r2.x * 64 + t * 16 + q];
    ushort4 v3 = nfb[(size_t)r3.x * 64 + t * 16 + q];
    acc.x += w0 * bf2f(v0.x) + w1 * bf2f(v1.x) + w2 * bf2f(v2.x) + w3 * bf2f(v3.x);
    acc.y += w0 * bf2f(v0.y) + w1 * bf2f(v1.y) + w2 * bf2f(v2.y) + w3 * bf2f(v3.y);
    acc.z += w0 * bf2f(v0.z) + w1 * bf2f(v1.z) + w2 * bf2f(v2.z) + w3 * bf2f(v3.z);
    acc.w += w0 * bf2f(v0.w) + w1 * bf2f(v1.w) + w2 * bf2f(v2.w) + w3 * bf2f(v3.w);
  }
  for (; p < end; ++p) {
    uint4 rr = rec[p];
    float w = __uint_as_float(((wsel ? rr.z : rr.y) >> wshift) << 16);
    ushort4 v = nfb[(size_t)rr.x * 64 + t * 16 + q];
    acc.x += w * bf2f(v.x); acc.y += w * bf2f(v.y);
    acc.z += w * bf2f(v.z); acc.w += w * bf2f(v.w);
  }
  float4 b = bias4[q];
  float4 res = make_float4(acc.x + b.x, acc.y + b.y, acc.z + b.z, acc.w + b.w);
  out4[(size_t)n * 64 + t * 16 + q] = res;   // regular cached store
}

// ---- f32 fallback path (small ws): records still bf16-weighted ----
__global__ __launch_bounds__(256) void gather_f32_kernel(
    const float4* __restrict__ nf4, const uint4* __restrict__ rec,
    const int* __restrict__ off, float4* __restrict__ h4, int N) {
  int idx = blockIdx.x * 256 + threadIdx.x;
  int n = idx >> 6;
  if (n >= N) return;
  int r = idx & 63, t = r >> 4, q = r & 15;
  int wsel = t >> 1;
  int wshift = (t & 1) << 4;
  int beg = off[n], end = off[n + 1];
  float4 acc = make_float4(0.f, 0.f, 0.f, 0.f);
  for (int p = beg; p < end; ++p) {
    uint4 rr = rec[p];
    float w = __uint_as_float(((wsel ? rr.z : rr.y) >> wshift) << 16);
    float4 v = nf4[(size_t)rr.x * 64 + t * 16 + q];
    acc.x += w * v.x; acc.y += w * v.y; acc.z += w * v.z; acc.w += w * v.w;
  }
  h4[(size_t)n * 64 + t * 16 + q] = acc;
}

__global__ __launch_bounds__(256) void linear_kernel(
    float* __restrict__ h, const float* __restrict__ W,
    const float* __restrict__ bias, int nrows) {
  __shared__ float Wt[64 * 65];
  __shared__ float rows[4][64];
  int tid = threadIdx.x;
  for (int i = tid; i < 4096; i += 256) Wt[(i & 63) * 65 + (i >> 6)] = W[i];
  int rr = tid >> 6, o = tid & 63;
  float b = bias[o];
  int rbase = blockIdx.x * 32;
  for (int r0 = 0; r0 < 32; r0 += 4) {
    int row = rbase + r0 + rr;
    __syncthreads();
    if (row < nrows) rows[rr][o] = h[(size_t)row * F_DIM + o];
    __syncthreads();
    if (row < nrows) {
      float acc = b;
      #pragma unroll
      for (int f = 0; f < 64; ++f) acc += rows[rr][f] * Wt[f * 65 + o];
      h[(size_t)row * F_DIM + o] = acc;
    }
  }
}

extern "C" void kernel_launch(void* const* d_in, const int* in_sizes, int n_in,
                              void* d_out, int out_size, void* d_ws, size_t ws_size,
                              hipStream_t stream) {
  const float* nf   = (const float*)d_in[0];
  const float* ew   = (const float*)d_in[1];
  const int*   src  = (const int*)d_in[2];
  const int*   dst  = (const int*)d_in[3];
  const float* W    = (const float*)d_in[4];
  const float* bias = (const float*)d_in[5];
  float* out = (float*)d_out;

  int E = in_sizes[2];
  int N = out_size / TF;
  int nrows = out_size / F_DIM;   // N*T
  int nfelems = nrows * F_DIM;

  // ws layout: [cnt N][off N+1][bsum 64] | rec uint4[E] | nfb (512B-aligned)
  char* wsb = (char*)d_ws;
  int* cnt  = (int*)wsb;
  int* off  = cnt + N;
  int* bsum = off + (N + 1);
  size_t ofs = ((size_t)(2 * N + 1 + 64) * 4 + 15) & ~(size_t)15;
  uint4* rec = (uint4*)(wsb + ofs);           ofs += (size_t)E * 16;
  ofs = (ofs + 511) & ~(size_t)511;           // row-align nfb: exact cachelines/row
  unsigned short* nfb = (unsigned short*)(wsb + ofs);
  size_t need_bf16 = ofs + (size_t)nfelems * 2;
  bool use_bf16 = ws_size >= need_bf16;

  (void)hipMemsetAsync(cnt, 0, (size_t)N * sizeof(int), stream);

  int eblk = (E + 255) / 256;
  hist_kernel<<<eblk, 256, 0, stream>>>(dst, cnt, E);

  int sblk = (N + 1023) / 1024;
  scanA_kernel<<<sblk, 1024, 0, stream>>>(cnt, off, bsum, N);
  scanB_kernel<<<1, 64, 0, stream>>>(bsum, sblk);
  scanC_kernel<<<(N + 1024) / 1024, 1024, 0, stream>>>(off, bsum, N, E);

  fill_kernel<<<eblk, 256, 0, stream>>>(dst, src, ew, off, cnt, rec, E);

  int gblk = (N * 64 + 255) / 256;
  if (use_bf16) {
    // 2048 blocks = 8 blocks/CU; ~24 rows/wave amortizes the per-wave W load.
    transform_kernel<<<2048, 256, 0, stream>>>(nf, W, nfb, nrows);
    gather_bf16_kernel<<<gblk, 256, 0, stream>>>(
        (const ushort4*)nfb, rec, off, (const float4*)bias, (float4*)out, N);
  } else {
    gather_f32_kernel<<<gblk, 256, 0, stream>>>(
        (const float4*)nf, rec, off, (float4*)out, N);
    linear_kernel<<<(nrows + 31) / 32, 256, 0, stream>>>(out, W, bias, nrows);
  }
}

// Round 9
// 192.743 us; speedup vs baseline: 14.2889x; 1.0907x over previous
//
#include <hip/hip_runtime.h>

// weighted_graph_conv, round 9: transform = R7's register-tiled LDS GEMM with
// the LDS cut to 49.3KB (rows[128][65]) -> 3 blocks/CU (R7: 83KB -> 1 block/CU,
// 8% occupancy). Thread tile 4 rows x 8 outputs; per f: 2 ds_read_b128 (Wt) +
// 4 broadcast b32 (rows) feed 32 FMA insts -> VALU-bound at 3 waves/SIMD.
// (R8's scalar-broadcast GEMV was latency-bound: serial s_load chain/row, 95us.)

#define F_DIM 64
#define TF 256  // T*F

__device__ __forceinline__ unsigned short f2bf(float x) {
  unsigned u = __float_as_uint(x);
  return (unsigned short)((u + 0x7FFF + ((u >> 16) & 1)) >> 16);  // RNE
}
__device__ __forceinline__ float bf2f(unsigned short b) {
  return __uint_as_float(((unsigned)b) << 16);
}
__device__ __forceinline__ void fma4(float4& a, float s, float4 w) {
  a.x += s * w.x; a.y += s * w.y; a.z += s * w.z; a.w += s * w.w;
}

__global__ __launch_bounds__(256) void hist_kernel(
    const int* __restrict__ dst, int* __restrict__ cnt, int E) {
  int e = blockIdx.x * 256 + threadIdx.x;
  if (e < E) atomicAdd(&cnt[dst[e]], 1);
}

__global__ __launch_bounds__(1024) void scanA_kernel(
    const int* __restrict__ cnt, int* __restrict__ off, int* __restrict__ bsum, int N) {
  __shared__ int wsum[16];
  int tid = threadIdx.x;
  int i = blockIdx.x * 1024 + tid;
  int v = (i < N) ? cnt[i] : 0;
  int lane = tid & 63;
  int incl = v;
  #pragma unroll
  for (int s = 1; s < 64; s <<= 1) {
    int t = __shfl_up(incl, s, 64);
    if (lane >= s) incl += t;
  }
  int w = tid >> 6;
  if (lane == 63) wsum[w] = incl;
  __syncthreads();
  if (w == 0) {
    int x = (lane < 16) ? wsum[lane] : 0;
    #pragma unroll
    for (int s = 1; s < 16; s <<= 1) {
      int t = __shfl_up(x, s, 64);
      if (lane >= s) x += t;
    }
    if (lane < 16) wsum[lane] = x;
  }
  __syncthreads();
  int wpre = (w == 0) ? 0 : wsum[w - 1];
  if (i < N) off[i] = wpre + incl - v;
  if (tid == 1023) bsum[blockIdx.x] = wpre + incl;
}

__global__ __launch_bounds__(64) void scanB_kernel(int* __restrict__ bsum, int nb) {
  int lane = threadIdx.x;
  int v = (lane < nb) ? bsum[lane] : 0;
  int incl = v;
  #pragma unroll
  for (int s = 1; s < 64; s <<= 1) {
    int t = __shfl_up(incl, s, 64);
    if (lane >= s) incl += t;
  }
  if (lane < nb) bsum[lane] = incl - v;
}

__global__ __launch_bounds__(1024) void scanC_kernel(
    int* __restrict__ off, const int* __restrict__ bsum, int N, int E) {
  int i = blockIdx.x * 1024 + threadIdx.x;
  if (i < N) off[i] += bsum[blockIdx.x];
  if (i == N) off[N] = E;
}

// CSR record: x=src, y=(w1|w0) bf16 pair, z=(w3|w2) bf16 pair, w=0.
__global__ __launch_bounds__(256) void fill_kernel(
    const int* __restrict__ dst, const int* __restrict__ src,
    const float* __restrict__ ew, const int* __restrict__ off,
    int* __restrict__ cnt, uint4* __restrict__ rec, int E) {
  int e = blockIdx.x * 256 + threadIdx.x;
  if (e < E) {
    int d = dst[e];
    int pos = off[d] + atomicSub(&cnt[d], 1) - 1;
    unsigned w0 = f2bf(ew[e]),         w1 = f2bf(ew[E + e]);
    unsigned w2 = f2bf(ew[2 * E + e]), w3 = f2bf(ew[3 * E + e]);
    uint4 r;
    r.x = (unsigned)src[e];
    r.y = (w1 << 16) | w0;
    r.z = (w3 << 16) | w2;
    r.w = 0;
    rec[pos] = r;   // single scattered 16B store, cached (L2/L3)
  }
}

// Transform: nfb[row,:] = bf16(W @ nf[row,:]).
// 128 rows/block in LDS (49.3KB total -> 3 blocks/CU); thread tile 4 rows x 8 outs.
__global__ __launch_bounds__(256) void transform_kernel(
    const float4* __restrict__ nf4, const float* __restrict__ W,
    unsigned short* __restrict__ nfb, int nrows) {
  __shared__ float Wt[64 * 64];     // Wt[f*64+o] = W[o*64+f]  (16 KB)
  __shared__ float rows[128][65];   // 33.3 KB, +1 pad
  int tid = threadIdx.x;
  #pragma unroll
  for (int i = tid; i < 4096; i += 256) Wt[(i & 63) * 64 + (i >> 6)] = W[i];
  int rbase = blockIdx.x * 128;
  int nr = min(128, nrows - rbase);
  for (int i = tid; i < nr * 16; i += 256) {
    int r = i >> 4, q = i & 15;
    float4 v = nf4[(size_t)(rbase + r) * 16 + q];
    rows[r][q * 4 + 0] = v.x; rows[r][q * 4 + 1] = v.y;
    rows[r][q * 4 + 2] = v.z; rows[r][q * 4 + 3] = v.w;
  }
  __syncthreads();

  int oq = tid & 7;          // output chunk: o in [oq*8, oq*8+8)
  int r0 = (tid >> 3) * 4;   // 4 rows per thread (32 groups x 4 = 128)
  float4 acc[4][2];
  #pragma unroll
  for (int j = 0; j < 4; ++j) {
    acc[j][0] = make_float4(0.f, 0.f, 0.f, 0.f);
    acc[j][1] = make_float4(0.f, 0.f, 0.f, 0.f);
  }

  const float4* Wt4 = (const float4*)Wt;  // Wt4[f*16 + o4]
  #pragma unroll 8
  for (int f = 0; f < 64; ++f) {
    float4 w0 = Wt4[f * 16 + oq * 2 + 0];   // 8 addrs/wave, 2-way bank (free)
    float4 w1 = Wt4[f * 16 + oq * 2 + 1];
    #pragma unroll
    for (int j = 0; j < 4; ++j) {
      float rv = rows[r0 + j][f];           // 8 addrs/wave, broadcast, conflict-free
      fma4(acc[j][0], rv, w0);
      fma4(acc[j][1], rv, w1);
    }
  }

  int obase = oq * 8;
  #pragma unroll
  for (int j = 0; j < 4; ++j) {
    if (r0 + j < nr) {
      size_t rowoff = (size_t)(rbase + r0 + j) * F_DIM + obase;
      #pragma unroll
      for (int c = 0; c < 2; ++c) {
        float4 a = acc[j][c];
        ushort4 u = make_ushort4(f2bf(a.x), f2bf(a.y), f2bf(a.z), f2bf(a.w));
        *reinterpret_cast<ushort4*>(&nfb[rowoff + c * 4]) = u;
      }
    }
  }
}

// One wave per node; lane r: t=r>>4, q=r&15. 4-wide unrolled gather.
__global__ __launch_bounds__(256) void gather_bf16_kernel(
    const ushort4* __restrict__ nfb, const uint4* __restrict__ rec,
    const int* __restrict__ off, const float4* __restrict__ bias4,
    float4* __restrict__ out4, int N) {
  int idx = blockIdx.x * 256 + threadIdx.x;
  int n = idx >> 6;
  if (n >= N) return;
  int r = idx & 63, t = r >> 4, q = r & 15;
  int wsel = t >> 1;            // 0: use rec.y, 1: use rec.z
  int wshift = (t & 1) << 4;    // 0 or 16
  int beg = off[n], end = off[n + 1];
  float4 acc = make_float4(0.f, 0.f, 0.f, 0.f);
  int p = beg;
  for (; p + 4 <= end; p += 4) {
    uint4 r0 = rec[p], r1 = rec[p + 1], r2 = rec[p + 2], r3 = rec[p + 3];
    float w0 = __uint_as_float(((wsel ? r0.z : r0.y) >> wshift) << 16);
    float w1 = __uint_as_float(((wsel ? r1.z : r1.y) >> wshift) << 16);
    float w2 = __uint_as_float(((wsel ? r2.z : r2.y) >> wshift) << 16);
    float w3 = __uint_as_float(((wsel ? r3.z : r3.y) >> wshift) << 16);
    ushort4 v0 = nfb[(size_t)r0.x * 64 + t * 16 + q];
    ushort4 v1 = nfb[(size_t)r1.x * 64 + t * 16 + q];
    ushort4 v2 = nfb[(size_t)r2.x * 64 + t * 16 + q];
    ushort4 v3 = nfb[(size_t)r3.x * 64 + t * 16 + q];
    acc.x += w0 * bf2f(v0.x) + w1 * bf2f(v1.x) + w2 * bf2f(v2.x) + w3 * bf2f(v3.x);
    acc.y += w0 * bf2f(v0.y) + w1 * bf2f(v1.y) + w2 * bf2f(v2.y) + w3 * bf2f(v3.y);
    acc.z += w0 * bf2f(v0.z) + w1 * bf2f(v1.z) + w2 * bf2f(v2.z) + w3 * bf2f(v3.z);
    acc.w += w0 * bf2f(v0.w) + w1 * bf2f(v1.w) + w2 * bf2f(v2.w) + w3 * bf2f(v3.w);
  }
  for (; p < end; ++p) {
    uint4 rr = rec[p];
    float w = __uint_as_float(((wsel ? rr.z : rr.y) >> wshift) << 16);
    ushort4 v = nfb[(size_t)rr.x * 64 + t * 16 + q];
    acc.x += w * bf2f(v.x); acc.y += w * bf2f(v.y);
    acc.z += w * bf2f(v.z); acc.w += w * bf2f(v.w);
  }
  float4 b = bias4[q];
  float4 res = make_float4(acc.x + b.x, acc.y + b.y, acc.z + b.z, acc.w + b.w);
  out4[(size_t)n * 64 + t * 16 + q] = res;   // regular cached store
}

// ---- f32 fallback path (small ws): records still bf16-weighted ----
__global__ __launch_bounds__(256) void gather_f32_kernel(
    const float4* __restrict__ nf4, const uint4* __restrict__ rec,
    const int* __restrict__ off, float4* __restrict__ h4, int N) {
  int idx = blockIdx.x * 256 + threadIdx.x;
  int n = idx >> 6;
  if (n >= N) return;
  int r = idx & 63, t = r >> 4, q = r & 15;
  int wsel = t >> 1;
  int wshift = (t & 1) << 4;
  int beg = off[n], end = off[n + 1];
  float4 acc = make_float4(0.f, 0.f, 0.f, 0.f);
  for (int p = beg; p < end; ++p) {
    uint4 rr = rec[p];
    float w = __uint_as_float(((wsel ? rr.z : rr.y) >> wshift) << 16);
    float4 v = nf4[(size_t)rr.x * 64 + t * 16 + q];
    acc.x += w * v.x; acc.y += w * v.y; acc.z += w * v.z; acc.w += w * v.w;
  }
  h4[(size_t)n * 64 + t * 16 + q] = acc;
}

__global__ __launch_bounds__(256) void linear_kernel(
    float* __restrict__ h, const float* __restrict__ W,
    const float* __restrict__ bias, int nrows) {
  __shared__ float Wt[64 * 65];
  __shared__ float rows[4][64];
  int tid = threadIdx.x;
  for (int i = tid; i < 4096; i += 256) Wt[(i & 63) * 65 + (i >> 6)] = W[i];
  int rr = tid >> 6, o = tid & 63;
  float b = bias[o];
  int rbase = blockIdx.x * 32;
  for (int r0 = 0; r0 < 32; r0 += 4) {
    int row = rbase + r0 + rr;
    __syncthreads();
    if (row < nrows) rows[rr][o] = h[(size_t)row * F_DIM + o];
    __syncthreads();
    if (row < nrows) {
      float acc = b;
      #pragma unroll
      for (int f = 0; f < 64; ++f) acc += rows[rr][f] * Wt[f * 65 + o];
      h[(size_t)row * F_DIM + o] = acc;
    }
  }
}

extern "C" void kernel_launch(void* const* d_in, const int* in_sizes, int n_in,
                              void* d_out, int out_size, void* d_ws, size_t ws_size,
                              hipStream_t stream) {
  const float* nf   = (const float*)d_in[0];
  const float* ew   = (const float*)d_in[1];
  const int*   src  = (const int*)d_in[2];
  const int*   dst  = (const int*)d_in[3];
  const float* W    = (const float*)d_in[4];
  const float* bias = (const float*)d_in[5];
  float* out = (float*)d_out;

  int E = in_sizes[2];
  int N = out_size / TF;
  int nrows = out_size / F_DIM;   // N*T
  int nfelems = nrows * F_DIM;

  // ws layout: [cnt N][off N+1][bsum 64] | rec uint4[E] | nfb (512B-aligned)
  char* wsb = (char*)d_ws;
  int* cnt  = (int*)wsb;
  int* off  = cnt + N;
  int* bsum = off + (N + 1);
  size_t ofs = ((size_t)(2 * N + 1 + 64) * 4 + 15) & ~(size_t)15;
  uint4* rec = (uint4*)(wsb + ofs);           ofs += (size_t)E * 16;
  ofs = (ofs + 511) & ~(size_t)511;           // row-align nfb: exact cachelines/row
  unsigned short* nfb = (unsigned short*)(wsb + ofs);
  size_t need_bf16 = ofs + (size_t)nfelems * 2;
  bool use_bf16 = ws_size >= need_bf16;

  (void)hipMemsetAsync(cnt, 0, (size_t)N * sizeof(int), stream);

  int eblk = (E + 255) / 256;
  hist_kernel<<<eblk, 256, 0, stream>>>(dst, cnt, E);

  int sblk = (N + 1023) / 1024;
  scanA_kernel<<<sblk, 1024, 0, stream>>>(cnt, off, bsum, N);
  scanB_kernel<<<1, 64, 0, stream>>>(bsum, sblk);
  scanC_kernel<<<(N + 1024) / 1024, 1024, 0, stream>>>(off, bsum, N, E);

  fill_kernel<<<eblk, 256, 0, stream>>>(dst, src, ew, off, cnt, rec, E);

  int gblk = (N * 64 + 255) / 256;
  if (use_bf16) {
    transform_kernel<<<(nrows + 127) / 128, 256, 0, stream>>>(
        (const float4*)nf, W, nfb, nrows);
    gather_bf16_kernel<<<gblk, 256, 0, stream>>>(
        (const ushort4*)nfb, rec, off, (const float4*)bias, (float4*)out, N);
  } else {
    gather_f32_kernel<<<gblk, 256, 0, stream>>>(
        (const float4*)nf, rec, off, (float4*)out, N);
    linear_kernel<<<(nrows + 31) / 32, 256, 0, stream>>>(out, W, bias, nrows);
  }
}